// Round 3
// baseline (2233.006 us; speedup 1.0000x reference)
//
#include <hip/hip_runtime.h>

#define V 512
#define L 168
#define PLANE 86016          // V*L
#define CHSTRIDE 2752512     // 32*512*168 elements per batch (x, h, out all share this)
#define NFLAT 5376           // 32*168
#define B_ 16
#define HDR (1u << 20)       // 1 MiB header for ATf (512*512*4 B)

// ---------------- prep: ATf[w][v] = (adj[v][w] + (v==w)) / d[v] ----------------
// d[v] = sum_w (adj[v][w] + delta) == a.sum(axis=1); row-normalized, stored transposed.
__global__ __launch_bounds__(256) void prep_f32(const float* __restrict__ adj,
                                                float* __restrict__ ATf) {
    const int v = blockIdx.x;
    float s = 0.f;
    for (int w = threadIdx.x; w < V; w += 256)
        s += adj[v * V + w] + (w == v ? 1.f : 0.f);
    __shared__ float red[256];
    red[threadIdx.x] = s;
    __syncthreads();
    for (int off = 128; off > 0; off >>= 1) {
        if ((int)threadIdx.x < off) red[threadIdx.x] += red[threadIdx.x + off];
        __syncthreads();
    }
    const float inv = 1.f / red[0];
    for (int w = threadIdx.x; w < V; w += 256)
        ATf[w * V + v] = (adj[v * V + w] + (w == v ? 1.f : 0.f)) * inv;
}

// ---------------- prop: hdst = 0.05*x + 0.95 * (ATf @ hsrc), all f32 -----------
// Per b: D[w(512), n(5376)] = ATf[512x512] * H[512 x 5376], n = c*L + l.
// Classic VALU SGEMM: 64x64 tile, 256 threads, 4x4 per thread, [k][m]-layout LDS.
__global__ __launch_bounds__(256) void prop_f32(const float* __restrict__ hsrc,
                                                const float* __restrict__ x,
                                                const float* __restrict__ ATf,
                                                float* __restrict__ hdst) {
    const int b = blockIdx.z, w0 = blockIdx.y * 64, n0 = blockIdx.x * 64;
    const int tid = threadIdx.x;
    __shared__ float As[64][68];   // As[k][m] = ATf[(w0+m)][v0+k]
    __shared__ float Bs[64][68];   // Bs[k][n] = hsrc[b][c(n)][v0+k][l(n)]
    const int tx = tid & 15, ty = tid >> 4;

    float acc[4][4] = {{0.f}};

    const int sn = tid & 63;
    const int nglob = n0 + sn;
    const int sc = nglob / L, sl = nglob - sc * L;
    const size_t bH = (size_t)b * CHSTRIDE;
    const size_t srcCol = bH + (size_t)sc * PLANE + sl;

    for (int v0 = 0; v0 < V; v0 += 64) {
        __syncthreads();
        {   // A-tile: lanes sweep k (coalesced global), m blocked per wave
            const int k = tid & 63;
            const int mb = (tid >> 6) * 16;
#pragma unroll
            for (int i = 0; i < 16; i++)
                As[k][mb + i] = ATf[(size_t)(w0 + mb + i) * V + v0 + k];
        }
        {   // B-tile: lanes sweep n (coalesced global), k blocked per wave
            const int kb = (tid >> 6) * 16;
#pragma unroll
            for (int i = 0; i < 16; i++)
                Bs[kb + i][sn] = hsrc[srcCol + (size_t)(v0 + kb + i) * L];
        }
        __syncthreads();
#pragma unroll 4
        for (int k = 0; k < 64; k++) {
            float a[4], bb[4];
#pragma unroll
            for (int i = 0; i < 4; i++) a[i] = As[k][ty * 4 + i];
#pragma unroll
            for (int j = 0; j < 4; j++) bb[j] = Bs[k][tx * 4 + j];
#pragma unroll
            for (int i = 0; i < 4; i++)
#pragma unroll
                for (int j = 0; j < 4; j++) acc[i][j] += a[i] * bb[j];
        }
    }

#pragma unroll
    for (int i = 0; i < 4; i++) {
        const int w = w0 + ty * 4 + i;
#pragma unroll
        for (int j = 0; j < 4; j++) {
            const int ncol = n0 + tx * 4 + j;
            const int c = ncol / L, l = ncol - c * L;
            const size_t off = bH + (size_t)c * PLANE + (size_t)w * L + l;
            hdst[off] = 0.05f * x[off] + 0.95f * acc[i][j];
        }
    }
}

// ---------------- outconv: out[o,pos] = bias[o] + sum_kc W[o,kc]*HO[kc,pos] ----
__global__ __launch_bounds__(256) void outconv_f32(const float* __restrict__ x,
                                                   const float* __restrict__ h1,
                                                   const float* __restrict__ h2,
                                                   const float* __restrict__ h3,
                                                   const float* __restrict__ W,
                                                   const float* __restrict__ bias,
                                                   float* __restrict__ out) {
    const int b = blockIdx.y, p0 = blockIdx.x * 64;
    const int tid = threadIdx.x;
    __shared__ float HOs[128][68];   // HOs[kc][pos]
    __shared__ float Ws[128][36];    // Ws[kc][o]
    const size_t bH = (size_t)b * CHSTRIDE;

    for (int idx = tid; idx < 4096; idx += 256) {
        const int o = idx >> 7, kc = idx & 127;
        Ws[kc][o] = W[idx];
    }
    {
        const int col = tid & 63;
        const int cb = (tid >> 6) * 8;
#pragma unroll
        for (int s = 0; s < 4; s++) {
            const float* src = (s == 0) ? x : (s == 1) ? h1 : (s == 2) ? h2 : h3;
#pragma unroll
            for (int i = 0; i < 8; i++)
                HOs[s * 32 + cb + i][col] = src[bH + (size_t)(cb + i) * PLANE + p0 + col];
        }
    }
    __syncthreads();

    const int o = tid >> 3;
    const int px = (tid & 7) * 8;
    float acc[8] = {0.f};
#pragma unroll 4
    for (int kc = 0; kc < 128; kc++) {
        const float wv = Ws[kc][o];
#pragma unroll
        for (int j = 0; j < 8; j++) acc[j] += wv * HOs[kc][px + j];
    }
    const float bv = bias[o];
#pragma unroll
    for (int j = 0; j < 8; j++)
        out[bH + (size_t)o * PLANE + p0 + px + j] = bv + acc[j];
}

// ---------------- ping-pong fallback: out (+)= W[:, 32s:32s+32] @ src ----------
__global__ __launch_bounds__(256) void outconv_slice(const float* __restrict__ src,
                                                     const float* __restrict__ W,
                                                     const float* __restrict__ bias,
                                                     float* __restrict__ out,
                                                     int s, int init) {
    const int b = blockIdx.y, p0 = blockIdx.x * 64;
    const int tid = threadIdx.x;
    __shared__ float HOs[32][68];
    __shared__ float Ws[32][36];
    const size_t bH = (size_t)b * CHSTRIDE;

    for (int idx = tid; idx < 1024; idx += 256) {
        const int o = idx >> 5, c = idx & 31;
        Ws[c][o] = W[o * 128 + s * 32 + c];
    }
    {
        const int col = tid & 63;
        const int cb = (tid >> 6) * 8;
#pragma unroll
        for (int i = 0; i < 8; i++)
            HOs[cb + i][col] = src[bH + (size_t)(cb + i) * PLANE + p0 + col];
    }
    __syncthreads();

    const int o = tid >> 3;
    const int px = (tid & 7) * 8;
    float acc[8] = {0.f};
#pragma unroll 4
    for (int c = 0; c < 32; c++) {
        const float wv = Ws[c][o];
#pragma unroll
        for (int j = 0; j < 8; j++) acc[j] += wv * HOs[c][px + j];
    }
#pragma unroll
    for (int j = 0; j < 8; j++) {
        const size_t idx = bH + (size_t)o * PLANE + p0 + px + j;
        out[idx] = (init ? bias[o] : out[idx]) + acc[j];
    }
}

extern "C" void kernel_launch(void* const* d_in, const int* in_sizes, int n_in,
                              void* d_out, int out_size, void* d_ws, size_t ws_size,
                              hipStream_t stream) {
    const float* x = (const float*)d_in[0];
    const float* adj = (const float*)d_in[1];
    const float* W = (const float*)d_in[2];
    const float* bias = (const float*)d_in[3];
    float* out = (float*)d_out;

    float* ATf = (float*)d_ws;
    float* hbuf = (float*)((char*)d_ws + HDR);

    prep_f32<<<V, 256, 0, stream>>>(adj, ATf);

    const size_t avail = ws_size > HDR ? ws_size - HDR : 0;
    const size_t perBuf = (size_t)CHSTRIDE * 4;    // f32 bytes per batch per h-buffer

    int nb3 = (int)(avail / (3 * perBuf));
    if (nb3 > B_) nb3 = B_;

    if (nb3 >= 1) {
        float* h1 = hbuf;
        float* h2 = hbuf + (size_t)nb3 * CHSTRIDE;
        float* h3 = hbuf + (size_t)2 * nb3 * CHSTRIDE;
        for (int b0 = 0; b0 < B_; b0 += nb3) {
            const int nb = (B_ - b0 < nb3) ? (B_ - b0) : nb3;
            const float* xb = x + (size_t)b0 * CHSTRIDE;
            float* outb = out + (size_t)b0 * CHSTRIDE;
            const dim3 pg(NFLAT / 64, V / 64, nb);
            const dim3 og(PLANE / 64, nb);
            prop_f32<<<pg, 256, 0, stream>>>(xb, xb, ATf, h1);
            prop_f32<<<pg, 256, 0, stream>>>(h1, xb, ATf, h2);
            prop_f32<<<pg, 256, 0, stream>>>(h2, xb, ATf, h3);
            outconv_f32<<<og, 256, 0, stream>>>(xb, h1, h2, h3, W, bias, outb);
        }
    } else {
        int nb2 = (int)(avail / (2 * perBuf));
        if (nb2 < 1) nb2 = 1;
        if (nb2 > B_) nb2 = B_;
        float* hA = hbuf;
        float* hB = hbuf + (size_t)nb2 * CHSTRIDE;
        for (int b0 = 0; b0 < B_; b0 += nb2) {
            const int nb = (B_ - b0 < nb2) ? (B_ - b0) : nb2;
            const float* xb = x + (size_t)b0 * CHSTRIDE;
            float* outb = out + (size_t)b0 * CHSTRIDE;
            const dim3 pg(NFLAT / 64, V / 64, nb);
            const dim3 og(PLANE / 64, nb);
            outconv_slice<<<og, 256, 0, stream>>>(xb, W, bias, outb, 0, 1);
            prop_f32<<<pg, 256, 0, stream>>>(xb, xb, ATf, hA);
            outconv_slice<<<og, 256, 0, stream>>>(hA, W, bias, outb, 1, 0);
            prop_f32<<<pg, 256, 0, stream>>>(hA, xb, ATf, hB);
            outconv_slice<<<og, 256, 0, stream>>>(hB, W, bias, outb, 2, 0);
            prop_f32<<<pg, 256, 0, stream>>>(hB, xb, ATf, hA);
            outconv_slice<<<og, 256, 0, stream>>>(hA, W, bias, outb, 3, 0);
        }
    }
}

// Round 4
// 1776.269 us; speedup vs baseline: 1.2571x; 1.2571x over previous
//
#include <hip/hip_runtime.h>

#define V 512
#define L 168
#define PLANE 86016          // V*L
#define CHSTRIDE 2752512     // 32*512*168 elements per batch (x, h, out all share this)
#define NFLAT 5376           // 32*168
#define B_ 16
#define HDR (1u << 20)       // 1 MiB header for ATf (512*512*4 B)

typedef __attribute__((ext_vector_type(8))) short s16x8;
typedef __attribute__((ext_vector_type(4))) float f32x4;

__device__ inline short f2bf(float f) {
    unsigned u = __builtin_bit_cast(unsigned, f);
    u += 0x7FFF + ((u >> 16) & 1);
    return (short)(u >> 16);
}

// ---------------- prep: ATf[w][v] = (adj[v][w] + (v==w)) / d[v] ----------------
__global__ __launch_bounds__(256) void prep_f32(const float* __restrict__ adj,
                                                float* __restrict__ ATf) {
    const int v = blockIdx.x;
    float s = 0.f;
    for (int w = threadIdx.x; w < V; w += 256)
        s += adj[v * V + w] + (w == v ? 1.f : 0.f);
    __shared__ float red[256];
    red[threadIdx.x] = s;
    __syncthreads();
    for (int off = 128; off > 0; off >>= 1) {
        if ((int)threadIdx.x < off) red[threadIdx.x] += red[threadIdx.x + off];
        __syncthreads();
    }
    const float inv = 1.f / red[0];
    for (int w = threadIdx.x; w < V; w += 256)
        ATf[w * V + v] = (adj[v * V + w] + (w == v ? 1.f : 0.f)) * inv;
}

// ---------------- prop (MFMA core, trusted skeleton): hdst = 0.05*x + 0.95*(AT@hsrc)
// Staging identical to the PASSING prop_f32: As[k][m], Bs[k][n], f32 LDS tiles.
// Only the inner product is new: bf16 MFMA 16x16x32 via builtin.
__global__ __launch_bounds__(256) void prop_mfma(const float* __restrict__ hsrc,
                                                 const float* __restrict__ x,
                                                 const float* __restrict__ ATf,
                                                 float* __restrict__ hdst) {
    const int b = blockIdx.z, w0 = blockIdx.y * 64, n0 = blockIdx.x * 64;
    const int tid = threadIdx.x;
    __shared__ float As[64][68];   // As[k][m] = ATf[(w0+m)][v0+k]
    __shared__ float Bs[64][68];   // Bs[k][n] = hsrc[b][c(n)][v0+k][l(n)]

    const int lane = tid & 63, wave = tid >> 6;
    const int colb = lane & 15, kg = lane >> 4;

    const int sn = tid & 63;
    const int nglob = n0 + sn;
    const int sc = nglob / L, sl = nglob - sc * L;
    const size_t bH = (size_t)b * CHSTRIDE;
    const size_t srcCol = bH + (size_t)sc * PLANE + sl;

    f32x4 acc[4];   // m-tiles {0,16,32,48} x n-tile [wave*16, wave*16+16)
#pragma unroll
    for (int i = 0; i < 4; i++) acc[i] = (f32x4){0.f, 0.f, 0.f, 0.f};

    for (int v0 = 0; v0 < V; v0 += 64) {
        __syncthreads();
        {   // A-tile (identical to trusted prop_f32)
            const int k = tid & 63;
            const int mb = (tid >> 6) * 16;
#pragma unroll
            for (int i = 0; i < 16; i++)
                As[k][mb + i] = ATf[(size_t)(w0 + mb + i) * V + v0 + k];
        }
        {   // B-tile (identical to trusted prop_f32)
            const int kb = (tid >> 6) * 16;
#pragma unroll
            for (int i = 0; i < 16; i++)
                Bs[kb + i][sn] = hsrc[srcCol + (size_t)(v0 + kb + i) * L];
        }
        __syncthreads();
#pragma unroll
        for (int kk = 0; kk < 2; kk++) {
            const int kb = kk * 32 + kg * 8;   // same k-slot mapping for A and B
            s16x8 bfr;
#pragma unroll
            for (int j = 0; j < 8; j++) bfr[j] = f2bf(Bs[kb + j][wave * 16 + colb]);
#pragma unroll
            for (int mt = 0; mt < 4; mt++) {
                s16x8 afr;
#pragma unroll
                for (int j = 0; j < 8; j++) afr[j] = f2bf(As[kb + j][mt * 16 + colb]);
                acc[mt] = __builtin_amdgcn_mfma_f32_16x16x32_bf16(afr, bfr, acc[mt], 0, 0, 0);
            }
        }
    }

    // epilogue: verified C/D layout col=lane&15, row=4*(lane>>4)+reg
#pragma unroll
    for (int mt = 0; mt < 4; mt++) {
        const int wrow0 = w0 + mt * 16 + kg * 4;
        const int ncol = n0 + wave * 16 + colb;
        const int c = ncol / L, l = ncol - c * L;
        const size_t base = bH + (size_t)c * PLANE + l;
#pragma unroll
        for (int r = 0; r < 4; r++) {
            const size_t off = base + (size_t)(wrow0 + r) * L;
            hdst[off] = 0.05f * x[off] + 0.95f * acc[mt][r];
        }
    }
}

// ---------------- outconv: out[o,pos] = bias[o] + sum_kc W[o,kc]*HO[kc,pos] ----
__global__ __launch_bounds__(256) void outconv_f32(const float* __restrict__ x,
                                                   const float* __restrict__ h1,
                                                   const float* __restrict__ h2,
                                                   const float* __restrict__ h3,
                                                   const float* __restrict__ W,
                                                   const float* __restrict__ bias,
                                                   float* __restrict__ out) {
    const int b = blockIdx.y, p0 = blockIdx.x * 64;
    const int tid = threadIdx.x;
    __shared__ float HOs[128][68];   // HOs[kc][pos]
    __shared__ float Ws[128][36];    // Ws[kc][o]
    const size_t bH = (size_t)b * CHSTRIDE;

    for (int idx = tid; idx < 4096; idx += 256) {
        const int o = idx >> 7, kc = idx & 127;
        Ws[kc][o] = W[idx];
    }
    {
        const int col = tid & 63;
        const int cb = (tid >> 6) * 8;
#pragma unroll
        for (int s = 0; s < 4; s++) {
            const float* src = (s == 0) ? x : (s == 1) ? h1 : (s == 2) ? h2 : h3;
#pragma unroll
            for (int i = 0; i < 8; i++)
                HOs[s * 32 + cb + i][col] = src[bH + (size_t)(cb + i) * PLANE + p0 + col];
        }
    }
    __syncthreads();

    const int o = tid >> 3;
    const int px = (tid & 7) * 8;
    float acc[8] = {0.f};
#pragma unroll 4
    for (int kc = 0; kc < 128; kc++) {
        const float wv = Ws[kc][o];
#pragma unroll
        for (int j = 0; j < 8; j++) acc[j] += wv * HOs[kc][px + j];
    }
    const float bv = bias[o];
#pragma unroll
    for (int j = 0; j < 8; j++)
        out[bH + (size_t)o * PLANE + p0 + px + j] = bv + acc[j];
}

// ---------------- ping-pong fallback: out (+)= W[:, 32s:32s+32] @ src ----------
__global__ __launch_bounds__(256) void outconv_slice(const float* __restrict__ src,
                                                     const float* __restrict__ W,
                                                     const float* __restrict__ bias,
                                                     float* __restrict__ out,
                                                     int s, int init) {
    const int b = blockIdx.y, p0 = blockIdx.x * 64;
    const int tid = threadIdx.x;
    __shared__ float HOs[32][68];
    __shared__ float Ws[32][36];
    const size_t bH = (size_t)b * CHSTRIDE;

    for (int idx = tid; idx < 1024; idx += 256) {
        const int o = idx >> 5, c = idx & 31;
        Ws[c][o] = W[o * 128 + s * 32 + c];
    }
    {
        const int col = tid & 63;
        const int cb = (tid >> 6) * 8;
#pragma unroll
        for (int i = 0; i < 8; i++)
            HOs[cb + i][col] = src[bH + (size_t)(cb + i) * PLANE + p0 + col];
    }
    __syncthreads();

    const int o = tid >> 3;
    const int px = (tid & 7) * 8;
    float acc[8] = {0.f};
#pragma unroll 4
    for (int c = 0; c < 32; c++) {
        const float wv = Ws[c][o];
#pragma unroll
        for (int j = 0; j < 8; j++) acc[j] += wv * HOs[c][px + j];
    }
#pragma unroll
    for (int j = 0; j < 8; j++) {
        const size_t idx = bH + (size_t)o * PLANE + p0 + px + j;
        out[idx] = (init ? bias[o] : out[idx]) + acc[j];
    }
}

extern "C" void kernel_launch(void* const* d_in, const int* in_sizes, int n_in,
                              void* d_out, int out_size, void* d_ws, size_t ws_size,
                              hipStream_t stream) {
    const float* x = (const float*)d_in[0];
    const float* adj = (const float*)d_in[1];
    const float* W = (const float*)d_in[2];
    const float* bias = (const float*)d_in[3];
    float* out = (float*)d_out;

    float* ATf = (float*)d_ws;
    float* hbuf = (float*)((char*)d_ws + HDR);

    prep_f32<<<V, 256, 0, stream>>>(adj, ATf);

    const size_t avail = ws_size > HDR ? ws_size - HDR : 0;
    const size_t perBuf = (size_t)CHSTRIDE * 4;    // f32 bytes per batch per h-buffer

    int nb3 = (int)(avail / (3 * perBuf));
    if (nb3 > B_) nb3 = B_;

    if (nb3 >= 1) {
        float* h1 = hbuf;
        float* h2 = hbuf + (size_t)nb3 * CHSTRIDE;
        float* h3 = hbuf + (size_t)2 * nb3 * CHSTRIDE;
        for (int b0 = 0; b0 < B_; b0 += nb3) {
            const int nb = (B_ - b0 < nb3) ? (B_ - b0) : nb3;
            const float* xb = x + (size_t)b0 * CHSTRIDE;
            float* outb = out + (size_t)b0 * CHSTRIDE;
            const dim3 pg(NFLAT / 64, V / 64, nb);
            const dim3 og(PLANE / 64, nb);
            prop_mfma<<<pg, 256, 0, stream>>>(xb, xb, ATf, h1);
            prop_mfma<<<pg, 256, 0, stream>>>(h1, xb, ATf, h2);
            prop_mfma<<<pg, 256, 0, stream>>>(h2, xb, ATf, h3);
            outconv_f32<<<og, 256, 0, stream>>>(xb, h1, h2, h3, W, bias, outb);
        }
    } else {
        int nb2 = (int)(avail / (2 * perBuf));
        if (nb2 < 1) nb2 = 1;
        if (nb2 > B_) nb2 = B_;
        float* hA = hbuf;
        float* hB = hbuf + (size_t)nb2 * CHSTRIDE;
        for (int b0 = 0; b0 < B_; b0 += nb2) {
            const int nb = (B_ - b0 < nb2) ? (B_ - b0) : nb2;
            const float* xb = x + (size_t)b0 * CHSTRIDE;
            float* outb = out + (size_t)b0 * CHSTRIDE;
            const dim3 pg(NFLAT / 64, V / 64, nb);
            const dim3 og(PLANE / 64, nb);
            outconv_slice<<<og, 256, 0, stream>>>(xb, W, bias, outb, 0, 1);
            prop_mfma<<<pg, 256, 0, stream>>>(xb, xb, ATf, hA);
            outconv_slice<<<og, 256, 0, stream>>>(hA, W, bias, outb, 1, 0);
            prop_mfma<<<pg, 256, 0, stream>>>(hA, xb, ATf, hB);
            outconv_slice<<<og, 256, 0, stream>>>(hB, W, bias, outb, 2, 0);
            prop_mfma<<<pg, 256, 0, stream>>>(hB, xb, ATf, hA);
            outconv_slice<<<og, 256, 0, stream>>>(hA, W, bias, outb, 3, 0);
        }
    }
}

// Round 5
// 629.661 us; speedup vs baseline: 3.5464x; 2.8210x over previous
//
#include <hip/hip_runtime.h>

#define V 512
#define L 168
#define PLANE 86016          // V*L
#define CHSTRIDE 2752512     // 32*512*168 elements per batch
#define NFLAT 5376           // 32*168
#define B_ 16
#define HDRB (1u << 20)      // ATb (512 KB) + Wb (8 KB), padded to 1 MiB

typedef __attribute__((ext_vector_type(8))) short s16x8;
typedef __attribute__((ext_vector_type(4))) float f32x4;
typedef unsigned short u16;

__device__ inline short f2bf(float f) {
    unsigned u = __builtin_bit_cast(unsigned, f);
    u += 0x7FFF + ((u >> 16) & 1);
    return (short)(u >> 16);
}
__device__ inline float bf2f(u16 s) {
    return __builtin_bit_cast(float, ((unsigned)s) << 16);
}

// ---------------- prep: ATb[w][v] = bf16((adj[v][w] + (v==w)) / d[v]); Wb ------
__global__ __launch_bounds__(256) void prep_b(const float* __restrict__ adj,
                                              const float* __restrict__ W,
                                              u16* __restrict__ ATb,
                                              u16* __restrict__ Wb) {
    if (blockIdx.x == V) {
        for (int i = threadIdx.x; i < 32 * 128; i += 256) Wb[i] = f2bf(W[i]);
        return;
    }
    const int v = blockIdx.x;
    float s = 0.f;
    for (int w = threadIdx.x; w < V; w += 256)
        s += adj[v * V + w] + (w == v ? 1.f : 0.f);
    __shared__ float red[256];
    red[threadIdx.x] = s;
    __syncthreads();
    for (int off = 128; off > 0; off >>= 1) {
        if ((int)threadIdx.x < off) red[threadIdx.x] += red[threadIdx.x + off];
        __syncthreads();
    }
    const float inv = 1.f / red[0];
    for (int w = threadIdx.x; w < V; w += 256)
        ATb[w * V + v] = f2bf((adj[v * V + w] + (w == v ? 1.f : 0.f)) * inv);
}

// ---------------- cvt: xa = bf16(x), vectorized ---------------------------------
__global__ __launch_bounds__(256) void cvt_bf16(const float* __restrict__ x,
                                                u16* __restrict__ xa, long n8) {
    long i = (long)blockIdx.x * 256 + threadIdx.x;
    const long stride = (long)gridDim.x * 256;
    for (; i < n8; i += stride) {
        const float4* p = (const float4*)(x + i * 8);
        const float4 a = p[0], b = p[1];
        s16x8 t;
        t[0] = f2bf(a.x); t[1] = f2bf(a.y); t[2] = f2bf(a.z); t[3] = f2bf(a.w);
        t[4] = f2bf(b.x); t[5] = f2bf(b.y); t[6] = f2bf(b.z); t[7] = f2bf(b.w);
        *(s16x8*)(xa + i * 8) = t;
    }
}

// ---------------- prop: hdst = bf16(0.05*xa + 0.95*(AT @ hsrc)) ----------------
// Block: D[w: 256][n: 64]; 4 waves, wave owns 64 w-rows x 64 n-cols.
// B-frags from interleaved LDS Hs[koct][n][8] (ds_read_b128, conflict-free);
// A-frags 16B direct from L2-resident ATb (k-contiguous rows).
__global__ __launch_bounds__(256, 2) void prop_b(const u16* __restrict__ hsrc,
                                                 const u16* __restrict__ xa,
                                                 const u16* __restrict__ ATb,
                                                 u16* __restrict__ hdst) {
    const int b = blockIdx.z, w0 = blockIdx.y * 256, n0 = blockIdx.x * 64;
    const int tid = threadIdx.x, lane = tid & 63, wave = tid >> 6;
    const int colb = lane & 15, kg = lane >> 4;
    __shared__ u16 Hs[8 * 64 * 8];   // [koct][n][j]: koct stride 512 elem (1 KB)

    const int sn = tid & 63;
    const int sc = (n0 + sn) / L, sl = (n0 + sn) - sc * L;
    const size_t bH = (size_t)b * CHSTRIDE;
    const size_t srcCol = bH + (size_t)sc * PLANE + sl;

    f32x4 acc[4][4];
#pragma unroll
    for (int i = 0; i < 4; i++)
#pragma unroll
        for (int j = 0; j < 4; j++) acc[i][j] = (f32x4){0.f, 0.f, 0.f, 0.f};

    for (int v0 = 0; v0 < V; v0 += 64) {
        __syncthreads();
#pragma unroll
        for (int h2 = 0; h2 < 2; h2++) {
            const int koct = wave + h2 * 4;
            s16x8 t;
#pragma unroll
            for (int j = 0; j < 8; j++)
                t[j] = (short)hsrc[srcCol + (size_t)(v0 + koct * 8 + j) * L];
            *(s16x8*)&Hs[koct * 512 + sn * 8] = t;
        }
        __syncthreads();
#pragma unroll
        for (int kk = 0; kk < 2; kk++) {
            s16x8 afr[4], bfr[4];
#pragma unroll
            for (int mt = 0; mt < 4; mt++)
                afr[mt] = *(const s16x8*)&ATb[(size_t)(w0 + wave * 64 + mt * 16 + colb) * V +
                                              v0 + kk * 32 + kg * 8];
#pragma unroll
            for (int nt = 0; nt < 4; nt++)
                bfr[nt] = *(const s16x8*)&Hs[(kk * 4 + kg) * 512 + (nt * 16 + colb) * 8];
#pragma unroll
            for (int mt = 0; mt < 4; mt++)
#pragma unroll
                for (int nt = 0; nt < 4; nt++)
                    acc[mt][nt] = __builtin_amdgcn_mfma_f32_16x16x32_bf16(afr[mt], bfr[nt],
                                                                          acc[mt][nt], 0, 0, 0);
        }
    }

    // epilogue (verified mapping): col n = nt*16+colb, rows w = wrow0..+3
#pragma unroll
    for (int mt = 0; mt < 4; mt++) {
        const int wrow0 = w0 + wave * 64 + mt * 16 + kg * 4;
#pragma unroll
        for (int nt = 0; nt < 4; nt++) {
            const int ncol = n0 + nt * 16 + colb;
            const int c = ncol / L, l = ncol - c * L;
            const size_t base = bH + (size_t)c * PLANE + l;
#pragma unroll
            for (int r = 0; r < 4; r++) {
                const size_t off = base + (size_t)(wrow0 + r) * L;
                hdst[off] = f2bf(0.05f * bf2f(xa[off]) + 0.95f * acc[mt][nt][r]);
            }
        }
    }
}

// ---------------- outconv: out = bias + W @ [xa,h1,h2,h3]  (MFMA) --------------
// Block: D[o: 32][pos: 64]; interleaved LDS HOs[m][pos][8], m = kc/8.
__global__ __launch_bounds__(256) void outconv_b(const u16* __restrict__ xa,
                                                 const u16* __restrict__ h1,
                                                 const u16* __restrict__ h2,
                                                 const u16* __restrict__ h3,
                                                 const u16* __restrict__ Wb,
                                                 const float* __restrict__ bias,
                                                 float* __restrict__ out) {
    const int b = blockIdx.y, p0 = blockIdx.x * 64;
    const int tid = threadIdx.x, lane = tid & 63, wave = tid >> 6;
    const int colb = lane & 15, kg = lane >> 4;
    __shared__ u16 Hs[16 * 64 * 8];  // 16 KB
    const size_t bH = (size_t)b * CHSTRIDE;
    const u16* bufs[4] = {xa, h1, h2, h3};

    {
        const int pos = tid & 63;
#pragma unroll
        for (int p = 0; p < 4; p++) {
            const int m = wave + p * 4;           // kc octet 0..15
            const u16* src = bufs[m >> 2] + bH + (size_t)((m & 3) * 8) * PLANE + p0 + pos;
            s16x8 t;
#pragma unroll
            for (int j = 0; j < 8; j++) t[j] = (short)src[(size_t)j * PLANE];
            *(s16x8*)&Hs[m * 512 + pos * 8] = t;
        }
    }
    __syncthreads();

    f32x4 acc[2];
    acc[0] = (f32x4){0.f, 0.f, 0.f, 0.f};
    acc[1] = acc[0];
#pragma unroll
    for (int kk = 0; kk < 4; kk++) {
        const s16x8 bfr = *(const s16x8*)&Hs[(kk * 4 + kg) * 512 + (wave * 16 + colb) * 8];
#pragma unroll
        for (int mt = 0; mt < 2; mt++) {
            const s16x8 afr = *(const s16x8*)&Wb[(mt * 16 + colb) * 128 + kk * 32 + kg * 8];
            acc[mt] = __builtin_amdgcn_mfma_f32_16x16x32_bf16(afr, bfr, acc[mt], 0, 0, 0);
        }
    }
#pragma unroll
    for (int mt = 0; mt < 2; mt++)
#pragma unroll
        for (int r = 0; r < 4; r++) {
            const int o = mt * 16 + kg * 4 + r;
            out[bH + (size_t)o * PLANE + p0 + wave * 16 + colb] = bias[o] + acc[mt][r];
        }
}

extern "C" void kernel_launch(void* const* d_in, const int* in_sizes, int n_in,
                              void* d_out, int out_size, void* d_ws, size_t ws_size,
                              hipStream_t stream) {
    const float* x = (const float*)d_in[0];
    const float* adj = (const float*)d_in[1];
    const float* W = (const float*)d_in[2];
    const float* bias = (const float*)d_in[3];
    float* out = (float*)d_out;

    char* ws = (char*)d_ws;
    u16* ATb = (u16*)ws;
    u16* Wb = (u16*)(ws + 524288);
    u16* hbuf = (u16*)(ws + HDRB);

    prep_b<<<V + 1, 256, 0, stream>>>(adj, W, ATb, Wb);

    const size_t perBuf = (size_t)CHSTRIDE * 2;          // bytes per batch per bf16 buffer
    const size_t avail = ws_size > HDRB ? ws_size - HDRB : 0;
    int nbc = (int)(avail / (4 * perBuf));               // xa + h1 + h2 + h3
    if (nbc < 1) nbc = 1;                                // requires ws >= ~23 MB
    if (nbc > B_) nbc = B_;

    for (int b0 = 0; b0 < B_; b0 += nbc) {
        const int nb = (B_ - b0 < nbc) ? (B_ - b0) : nbc;
        const float* xb = x + (size_t)b0 * CHSTRIDE;
        float* outb = out + (size_t)b0 * CHSTRIDE;
        u16* xa = hbuf;
        u16* h1 = hbuf + (size_t)nbc * CHSTRIDE;
        u16* h2 = hbuf + (size_t)2 * nbc * CHSTRIDE;
        u16* h3 = hbuf + (size_t)3 * nbc * CHSTRIDE;

        const long n8 = (long)nb * CHSTRIDE / 8;
        cvt_bf16<<<2048, 256, 0, stream>>>(xb, xa, n8);

        const dim3 pg(NFLAT / 64, 2, nb);                // (84, 2, nb)
        const dim3 og(PLANE / 64, nb);                   // (1344, nb)
        prop_b<<<pg, 256, 0, stream>>>(xa, xa, ATb, h1);
        prop_b<<<pg, 256, 0, stream>>>(h1, xa, ATb, h2);
        prop_b<<<pg, 256, 0, stream>>>(h2, xa, ATb, h3);
        outconv_b<<<og, 256, 0, stream>>>(xa, h1, h2, h3, Wb, bias, outb);
    }
}

// Round 6
// 564.674 us; speedup vs baseline: 3.9545x; 1.1151x over previous
//
#include <hip/hip_runtime.h>

#define V 512
#define L 168
#define PLANE 86016          // V*L
#define CHSTRIDE 2752512     // 32*512*168 elements per batch
#define NFLAT 5376           // 32*168
#define B_ 16
#define HDRB (1u << 20)      // ATb (512 KB) + Wb (8 KB), padded to 1 MiB

typedef __attribute__((ext_vector_type(8))) short s16x8;
typedef __attribute__((ext_vector_type(4))) float f32x4;
typedef unsigned short u16;

__device__ inline short f2bf(float f) {
    unsigned u = __builtin_bit_cast(unsigned, f);
    u += 0x7FFF + ((u >> 16) & 1);
    return (short)(u >> 16);
}

// ---- prep: ATb[w][v] = bf16(rownorm adj^T); Wb = folded W' (mix absorbed) ----
// out = b + W0'p0 + W1'p1 + W2'p2 + W3'p3,  p0=x, pk=A p_{k-1}
// W0'=W0+a(W1+W2+W3)  W1'=be(W1+a(W2+W3))  W2'=be^2(W2+aW3)  W3'=be^3 W3
__global__ __launch_bounds__(256) void prep_b(const float* __restrict__ adj,
                                              const float* __restrict__ W,
                                              u16* __restrict__ ATb,
                                              u16* __restrict__ Wb) {
    if (blockIdx.x == V) {
        const float al = 0.05f, be = 0.95f;
        for (int i = threadIdx.x; i < 1024; i += 256) {
            const int o = i >> 5, c = i & 31;
            const float w0 = W[o * 128 + c];
            const float w1 = W[o * 128 + 32 + c];
            const float w2 = W[o * 128 + 64 + c];
            const float w3 = W[o * 128 + 96 + c];
            Wb[o * 128 + c]      = f2bf(w0 + al * (w1 + w2 + w3));
            Wb[o * 128 + 32 + c] = f2bf(be * (w1 + al * (w2 + w3)));
            Wb[o * 128 + 64 + c] = f2bf(be * be * (w2 + al * w3));
            Wb[o * 128 + 96 + c] = f2bf(be * be * be * w3);
        }
        return;
    }
    const int v = blockIdx.x;
    float s = 0.f;
    for (int w = threadIdx.x; w < V; w += 256)
        s += adj[v * V + w] + (w == v ? 1.f : 0.f);
    __shared__ float red[256];
    red[threadIdx.x] = s;
    __syncthreads();
    for (int off = 128; off > 0; off >>= 1) {
        if ((int)threadIdx.x < off) red[threadIdx.x] += red[threadIdx.x + off];
        __syncthreads();
    }
    const float inv = 1.f / red[0];
    for (int w = threadIdx.x; w < V; w += 256)
        ATb[w * V + v] = f2bf((adj[v * V + w] + (w == v ? 1.f : 0.f)) * inv);
}

// ---- prop: dst = bf16(AT @ src) — PURE GEMM, double-buffered staging ----------
// Block: D[w: 256][n: 64]; 4 waves; wave owns 64 w x 64 n.
// B-staging: regs prefetched for next v0-step while MFMA runs (T14 split),
// one barrier per iter (dbuf hazard argument: W(b_i)..BAR_i..R(b_i); next
// write to b_i is in iter i+2, after BAR_{i+1} which follows all R(b_i)).
template <bool SRCF32>
__global__ __launch_bounds__(256, 2) void prop_p(const void* __restrict__ src,
                                                 const u16* __restrict__ ATb,
                                                 u16* __restrict__ dst) {
    const int b = blockIdx.z, w0 = blockIdx.y * 256, n0 = blockIdx.x * 64;
    const int tid = threadIdx.x, lane = tid & 63, wave = tid >> 6;
    const int colb = lane & 15, kg = lane >> 4;
    __shared__ u16 Hs[2][8 * 64 * 8];   // [buf][koct][n][8j], koct stride 512

    const int sn = tid & 63;
    const int sc = (n0 + sn) / L, sl = (n0 + sn) - sc * L;
    const size_t bH = (size_t)b * CHSTRIDE;
    const size_t srcCol = bH + (size_t)sc * PLANE + sl;

    f32x4 acc[4][4];
#pragma unroll
    for (int i = 0; i < 4; i++)
#pragma unroll
        for (int j = 0; j < 4; j++) acc[i][j] = (f32x4){0.f, 0.f, 0.f, 0.f};

    s16x8 t0, t1;   // staged kocts: wave, wave+4
#define LOADT(v0base)                                                              \
    {                                                                              \
        _Pragma("unroll") for (int j = 0; j < 8; j++) {                            \
            const size_t o0 = srcCol + (size_t)((v0base) + wave * 8 + j) * L;      \
            const size_t o1 = srcCol + (size_t)((v0base) + 32 + wave * 8 + j) * L; \
            if (SRCF32) {                                                          \
                t0[j] = f2bf(((const float*)src)[o0]);                             \
                t1[j] = f2bf(((const float*)src)[o1]);                             \
            } else {                                                               \
                t0[j] = (short)((const u16*)src)[o0];                              \
                t1[j] = (short)((const u16*)src)[o1];                              \
            }                                                                      \
        }                                                                          \
    }

    LOADT(0);
    int buf = 0;
    for (int v0 = 0; v0 < V; v0 += 64) {
        *(s16x8*)&Hs[buf][wave * 512 + sn * 8] = t0;
        *(s16x8*)&Hs[buf][(wave + 4) * 512 + sn * 8] = t1;
        __syncthreads();
        if (v0 + 64 < V) LOADT(v0 + 64);   // overlap next loads with MFMA
#pragma unroll
        for (int kk = 0; kk < 2; kk++) {
            s16x8 afr[4], bfr[4];
#pragma unroll
            for (int mt = 0; mt < 4; mt++)
                afr[mt] = *(const s16x8*)&ATb[(size_t)(w0 + wave * 64 + mt * 16 + colb) * V +
                                              v0 + kk * 32 + kg * 8];
#pragma unroll
            for (int nt = 0; nt < 4; nt++)
                bfr[nt] = *(const s16x8*)&Hs[buf][(kk * 4 + kg) * 512 + (nt * 16 + colb) * 8];
#pragma unroll
            for (int mt = 0; mt < 4; mt++)
#pragma unroll
                for (int nt = 0; nt < 4; nt++)
                    acc[mt][nt] = __builtin_amdgcn_mfma_f32_16x16x32_bf16(afr[mt], bfr[nt],
                                                                          acc[mt][nt], 0, 0, 0);
        }
        buf ^= 1;
    }
#undef LOADT

    // epilogue: pure bf16 store (verified D mapping: col=lane&15, row=4*kg+r)
#pragma unroll
    for (int mt = 0; mt < 4; mt++) {
        const int wrow0 = w0 + wave * 64 + mt * 16 + kg * 4;
#pragma unroll
        for (int nt = 0; nt < 4; nt++) {
            const int ncol = n0 + nt * 16 + colb;
            const int c = ncol / L, l = ncol - c * L;
            const size_t base = bH + (size_t)c * PLANE + l;
#pragma unroll
            for (int r = 0; r < 4; r++)
                dst[base + (size_t)(wrow0 + r) * L] = f2bf(acc[mt][nt][r]);
        }
    }
}

// ---- outconv: out = bias + W' @ [x(f32), p1, p2, p3] --------------------------
__global__ __launch_bounds__(256) void outconv_b(const float* __restrict__ x,
                                                 const u16* __restrict__ p1,
                                                 const u16* __restrict__ p2,
                                                 const u16* __restrict__ p3,
                                                 const u16* __restrict__ Wb,
                                                 const float* __restrict__ bias,
                                                 float* __restrict__ out) {
    const int b = blockIdx.y, p0 = blockIdx.x * 64;
    const int tid = threadIdx.x, lane = tid & 63, wave = tid >> 6;
    const int colb = lane & 15, kg = lane >> 4;
    __shared__ u16 Hs[16 * 64 * 8];  // 16 KB
    const size_t bH = (size_t)b * CHSTRIDE;
    const u16* bufs[4] = {nullptr, p1, p2, p3};

    {
        const int pos = tid & 63;
#pragma unroll
        for (int p = 0; p < 4; p++) {
            const int m = wave + p * 4;     // kc octet; s = m>>2 == p (wave<4)
            s16x8 t;
            if (p == 0) {
                const float* srcx = x + bH + (size_t)((m & 3) * 8) * PLANE + p0 + pos;
#pragma unroll
                for (int j = 0; j < 8; j++) t[j] = f2bf(srcx[(size_t)j * PLANE]);
            } else {
                const u16* srch = bufs[p] + bH + (size_t)((m & 3) * 8) * PLANE + p0 + pos;
#pragma unroll
                for (int j = 0; j < 8; j++) t[j] = (short)srch[(size_t)j * PLANE];
            }
            *(s16x8*)&Hs[m * 512 + pos * 8] = t;
        }
    }
    __syncthreads();

    f32x4 acc[2];
    acc[0] = (f32x4){0.f, 0.f, 0.f, 0.f};
    acc[1] = acc[0];
#pragma unroll
    for (int kk = 0; kk < 4; kk++) {
        const s16x8 bfr = *(const s16x8*)&Hs[(kk * 4 + kg) * 512 + (wave * 16 + colb) * 8];
#pragma unroll
        for (int mt = 0; mt < 2; mt++) {
            const s16x8 afr = *(const s16x8*)&Wb[(mt * 16 + colb) * 128 + kk * 32 + kg * 8];
            acc[mt] = __builtin_amdgcn_mfma_f32_16x16x32_bf16(afr, bfr, acc[mt], 0, 0, 0);
        }
    }
#pragma unroll
    for (int mt = 0; mt < 2; mt++)
#pragma unroll
        for (int r = 0; r < 4; r++) {
            const int o = mt * 16 + kg * 4 + r;
            out[bH + (size_t)o * PLANE + p0 + wave * 16 + colb] = bias[o] + acc[mt][r];
        }
}

extern "C" void kernel_launch(void* const* d_in, const int* in_sizes, int n_in,
                              void* d_out, int out_size, void* d_ws, size_t ws_size,
                              hipStream_t stream) {
    const float* x = (const float*)d_in[0];
    const float* adj = (const float*)d_in[1];
    const float* W = (const float*)d_in[2];
    const float* bias = (const float*)d_in[3];
    float* out = (float*)d_out;

    char* ws = (char*)d_ws;
    u16* ATb = (u16*)ws;
    u16* Wb = (u16*)(ws + 524288);
    u16* hbuf = (u16*)(ws + HDRB);

    prep_b<<<V + 1, 256, 0, stream>>>(adj, W, ATb, Wb);

    const size_t perBuf = (size_t)CHSTRIDE * 2;          // bytes per batch per bf16 buffer
    const size_t avail = ws_size > HDRB ? ws_size - HDRB : 0;
    int nbc = (int)(avail / (3 * perBuf));               // p1 + p2 + p3
    if (nbc < 1) nbc = 1;                                // requires ws >= ~17.5 MB
    if (nbc > B_) nbc = B_;

    for (int b0 = 0; b0 < B_; b0 += nbc) {
        const int nb = (B_ - b0 < nbc) ? (B_ - b0) : nbc;
        const float* xb = x + (size_t)b0 * CHSTRIDE;
        float* outb = out + (size_t)b0 * CHSTRIDE;
        u16* p1 = hbuf;
        u16* p2 = hbuf + (size_t)nbc * CHSTRIDE;
        u16* p3 = hbuf + (size_t)2 * nbc * CHSTRIDE;

        const dim3 pg(NFLAT / 64, 2, nb);                // (84, 2, nb)
        const dim3 og(PLANE / 64, nb);                   // (1344, nb)
        prop_p<true><<<pg, 256, 0, stream>>>((const void*)xb, ATb, p1);
        prop_p<false><<<pg, 256, 0, stream>>>((const void*)p1, ATb, p2);
        prop_p<false><<<pg, 256, 0, stream>>>((const void*)p2, ATb, p3);
        outconv_b<<<og, 256, 0, stream>>>(xb, p1, p2, p3, Wb, bias, outb);
    }
}